// Round 6
// baseline (273.593 us; speedup 1.0000x reference)
//
#include <hip/hip_runtime.h>

#define NQ    12
#define DIM   4096
#define DEPTH 6
#define BLK   256     // 4 waves; one batch element per block
#define NT    4       // 16-column tiles per wave (4 waves * 4 * 16 = 256 cols)

// ---------------------------------------------------------------------------
// MFMA formulation. Wire i <-> q-bit (11-i). Per layer, 3 sweeps each apply a
// 16x16 complex U (tensor product of 4 fused RX*RZ*RY gates) to S[16][256]:
//   P0: l=q[3:0] (wires 8-11), c=q[11:4]
//   P1: l=q[7:4] (wires 4-7),  c=q[11:8]<<4|q[3:0]
//   P2: l=q[11:8](wires 0-3),  c=q[7:0]
// K=32 packing: B=[Sr;Si]; Cr=[Ur|-Ui]*B, Ci=[Ui|Ur]*B; fp32 split into
// bf16 hi+lo -> 3 MFMA per output component per tile (drop lo*lo ~2^-18).
// State lives in LDS between sweeps as u32 = bf16hi | bf16lo<<16 at
//   pa(c,comp,l) = c*128 + (((comp*4+(l>>2)) ^ (c&7) ^ ((c>>4)&7))*16) + (l&3)*4
// pa is XOR-linear in (c,l) -> producer writes = base ^ constexpr mask per
// output row; the 11-CNOT chain (suffix-xor C) folds into the P2->P0 write
// address, zero instructions. MFMA frag layouts: A row=lane&15,k=8*(lane>>4)+e;
// B col=lane&15, same k; D col=lane&15, row=(lane>>4)*4+reg (HW-verified).
// A-matrices prebuilt per sweep into d_ws by prep_kernel (72 KB).
// ---------------------------------------------------------------------------

typedef __attribute__((ext_vector_type(8))) short bfrag;
typedef __attribute__((ext_vector_type(4))) float f32x4v;
typedef __attribute__((ext_vector_type(4))) int   i32x4v;
typedef __attribute__((ext_vector_type(2))) unsigned u32x2v;

__device__ __host__ __forceinline__ constexpr int sfx4(int v) {   // 4-bit suffix-xor
  v &= 15; v ^= v >> 1; v ^= v >> 2; return v & 15;
}
__device__ __host__ __forceinline__ constexpr int sfx8(int v) {   // 8-bit suffix-xor
  v &= 255; v ^= v >> 1; v ^= v >> 2; v ^= v >> 4; return v & 255;
}
__device__ __host__ __forceinline__ constexpr int par4(int v) {
  return __builtin_popcount((unsigned)v) & 1;
}
// LDS byte address of u32 element (c, comp, l); fields disjoint -> XOR-linear
__device__ __forceinline__ int pa(int c, int comp, int l) {
  int uu = (comp << 2) | (l >> 2);
  uu = (uu ^ (c & 7) ^ ((c >> 4) & 7)) & 7;
  return (c << 7) + (uu << 4) + ((l & 3) << 2);
}
// XOR-delta of pa under (c ^= cd, l ^= ld)
__device__ __host__ __forceinline__ constexpr int pa0(int cd, int ld) {
  return (cd << 7) ^ (((((cd & 7) ^ ((cd >> 4) & 7)) ^ ((ld >> 2) & 3)) & 7) << 4)
                   ^ ((ld & 3) << 2);
}
// producer write-address delta for output row offset dd, per source sweep P
__device__ __host__ __forceinline__ constexpr int prodK(int P, int dd) {
  return (P == 0) ? pa0(dd, 0)
       : (P == 1) ? pa0(dd << 4, 0)
       : pa0((sfx4(dd) << 4) | (par4(dd) * 15), par4(dd) * 15);
}
__device__ __host__ __forceinline__ constexpr int qK(int dd) {    // final-layer q'' delta
  return (sfx4(dd) << 8) | (par4(dd) * 255);
}

// fp32 -> packed (bf16 hi | bf16 lo << 16), RNE both halves, pure bit-ops
__device__ __forceinline__ unsigned rne16(unsigned u) {
  return (u + 0x7FFFu + ((u >> 16) & 1u)) >> 16;
}
__device__ __forceinline__ unsigned packsplit(float x) {
  const unsigned u = __float_as_uint(x);
  const unsigned h = rne16(u);
  const float hf = __uint_as_float(h << 16);
  const unsigned l = rne16(__float_as_uint(x - hf));
  return h | (l << 16);
}

// ---- prep: per sweep, build A fragments [s18][mx: rHi,rLo,iHi,iLo][lane] ----
__global__ void prep_kernel(const float* __restrict__ params, float* __restrict__ gt) {
  const int s18 = blockIdx.x;          // 0..17
  const int d = s18 / 3, p = s18 % 3;
  const int L = threadIdx.x;           // 0..63
  __shared__ float G[4][8];            // fused gate per local bit b (wire 11-4p-b)
  if (L < 4) {
    const int wire = 11 - 4 * p - L;
    const float py = params[(d * NQ + wire) * 3 + 0];
    const float pz = params[(d * NQ + wire) * 3 + 1];
    const float px = params[(d * NQ + wire) * 3 + 2];
    float sa, ca, sb, cb, sg, cg;
    __sincosf(py * 0.5f, &sa, &ca);
    __sincosf(pz * 0.5f, &sb, &cb);
    __sincosf(px * 0.5f, &sg, &cg);
    const float Ar = ca * cb, Ai = -ca * sb;
    const float Br = -sa * cb, Bi = sa * sb;
    const float Cr = sa * cb, Ci = sa * sb;
    const float Dr = ca * cb, Di = ca * sb;
    float* u = G[L];                   // [row][col] -> (row*2+col)*2 + {re,im}
    u[0] = cg * Ar + sg * Ci;  u[1] = cg * Ai - sg * Cr;   // u00
    u[2] = cg * Br + sg * Di;  u[3] = cg * Bi - sg * Dr;   // u01
    u[4] = sg * Ai + cg * Cr;  u[5] = -sg * Ar + cg * Ci;  // u10
    u[6] = sg * Bi + cg * Dr;  u[7] = -sg * Br + cg * Di;  // u11
  }
  __syncthreads();
  const int r = L & 15, kg = L >> 4;   // A row, k-group (k = 8*kg + e)
  unsigned short frag[4][8];
#pragma unroll
  for (int e = 0; e < 8; ++e) {
    const int kk = ((kg & 1) << 3) | e;        // column of U within 16
    float cr = 1.f, ci = 0.f;                  // U16[r][kk] = prod of 4 gate entries
#pragma unroll
    for (int bb = 0; bb < 4; ++bb) {
      const int cell = (((r >> bb) & 1) * 2 + ((kk >> bb) & 1)) * 2;
      const float ar = G[bb][cell], ai = G[bb][cell + 1];
      const float nr = cr * ar - ci * ai;
      const float ni = cr * ai + ci * ar;
      cr = nr; ci = ni;
    }
    // A_r[r][k]: k<16 -> Ur, k>=16 -> -Ui.  A_i[r][k]: k<16 -> Ui, k>=16 -> Ur.
    const float vr = (kg >= 2) ? -ci : cr;
    const float vi = (kg >= 2) ?  cr : ci;
    const unsigned wr = packsplit(vr);
    const unsigned wi = packsplit(vi);
    frag[0][e] = (unsigned short)(wr & 0xFFFFu);
    frag[1][e] = (unsigned short)(wr >> 16);
    frag[2][e] = (unsigned short)(wi & 0xFFFFu);
    frag[3][e] = (unsigned short)(wi >> 16);
  }
#pragma unroll
  for (int mx = 0; mx < 4; ++mx) {
    const unsigned q0 = (unsigned)frag[mx][0] | ((unsigned)frag[mx][1] << 16);
    const unsigned q1 = (unsigned)frag[mx][2] | ((unsigned)frag[mx][3] << 16);
    const unsigned q2 = (unsigned)frag[mx][4] | ((unsigned)frag[mx][5] << 16);
    const unsigned q3 = (unsigned)frag[mx][6] | ((unsigned)frag[mx][7] << 16);
    i32x4v vv = { (int)q0, (int)q1, (int)q2, (int)q3 };
    *(i32x4v*)((char*)gt + (((s18 * 4 + mx) * 64) + L) * 16) = vv;
  }
}

// ---- one sweep: read B-frags, 6 MFMA per tile, split+scatter to next layout
template <int P, bool FINAL>
__device__ __forceinline__ void do_sweep(int d, const float* __restrict__ gt,
                                         char* smb, int T) {
  const int lane = T & 63, wv = T >> 6;
  const int n = lane & 15, g = lane >> 4;
  const int comp = lane >> 5, lhalf = g & 1;
  const int s18 = d * 3 + P;

  const i32x4v* gp = (const i32x4v*)gt + (s18 * 4) * 64 + lane;
  const bfrag A0 = __builtin_bit_cast(bfrag, gp[0]);     // [Ur|-Ui] hi
  const bfrag A1 = __builtin_bit_cast(bfrag, gp[64]);    // [Ur|-Ui] lo
  const bfrag A2 = __builtin_bit_cast(bfrag, gp[128]);   // [Ui| Ur] hi
  const bfrag A3 = __builtin_bit_cast(bfrag, gp[192]);   // [Ui| Ur] lo

  i32x4v ra[NT], rb[NT];
#pragma unroll
  for (int t = 0; t < NT; ++t) {
    const int TT = wv * NT + t;
    const int a0 = pa(TT * 16 + n, comp, lhalf * 8);
    ra[t] = *(const i32x4v*)(smb + a0);
    rb[t] = *(const i32x4v*)(smb + (a0 ^ 16));
  }
  __syncthreads();   // WAR: every wave's reads complete before any write below

#pragma unroll
  for (int t = 0; t < NT; ++t) {
    const int TT = wv * NT + t;
    unsigned hh[4], ll[4];
#pragma unroll
    for (int i = 0; i < 2; ++i) {
      const unsigned a = (unsigned)ra[t][2 * i], b2 = (unsigned)ra[t][2 * i + 1];
      const unsigned c = (unsigned)rb[t][2 * i], d2 = (unsigned)rb[t][2 * i + 1];
      hh[i]     = (a & 0xFFFFu) | (b2 << 16);
      ll[i]     = (a >> 16)     | (b2 & 0xFFFF0000u);
      hh[i + 2] = (c & 0xFFFFu) | (d2 << 16);
      ll[i + 2] = (c >> 16)     | (d2 & 0xFFFF0000u);
    }
    i32x4v hv = { (int)hh[0], (int)hh[1], (int)hh[2], (int)hh[3] };
    i32x4v lv = { (int)ll[0], (int)ll[1], (int)ll[2], (int)ll[3] };
    const bfrag BH = __builtin_bit_cast(bfrag, hv);
    const bfrag BL = __builtin_bit_cast(bfrag, lv);

    f32x4v cr = { 0.f, 0.f, 0.f, 0.f }, ci = { 0.f, 0.f, 0.f, 0.f };
    cr = __builtin_amdgcn_mfma_f32_16x16x32_bf16(A0, BH, cr, 0, 0, 0);
    cr = __builtin_amdgcn_mfma_f32_16x16x32_bf16(A0, BL, cr, 0, 0, 0);
    cr = __builtin_amdgcn_mfma_f32_16x16x32_bf16(A1, BH, cr, 0, 0, 0);
    ci = __builtin_amdgcn_mfma_f32_16x16x32_bf16(A2, BH, ci, 0, 0, 0);
    ci = __builtin_amdgcn_mfma_f32_16x16x32_bf16(A2, BL, ci, 0, 0, 0);
    ci = __builtin_amdgcn_mfma_f32_16x16x32_bf16(A3, BH, ci, 0, 0, 0);

    if (!FINAL) {
      int base;
      if (P == 0) {
        base = pa((TT << 4) | (g << 2), 0, n);            // -> P1 layout
      } else if (P == 1) {
        base = pa((g << 6) | n, 0, TT);                   // -> P2 layout
      } else {                                            // -> P0 layout + CNOT
        const int S8 = sfx8((TT << 4) | n);
        const int PM = ((g ^ (g >> 1)) & 1) ? 15 : 0;
        const int cb = (sfx4(g << 2) << 4) | (((S8 >> 4) ^ PM) & 15);
        const int lb = (S8 ^ PM) & 15;
        base = pa(cb, 0, lb);
      }
#pragma unroll
      for (int dd = 0; dd < 4; ++dd) {
        *(unsigned*)(smb + (base ^ prodK(P, dd)))        = packsplit(cr[dd]);
        *(unsigned*)(smb + (base ^ prodK(P, dd) ^ 64))   = packsplit(ci[dd]);
      }
    } else {  // last layer P2: write |amp|^2 at plain f32[q''] (CNOT folded)
      const int S8 = sfx8((TT << 4) | n);
      const int PM = ((g ^ (g >> 1)) & 1) ? 15 : 0;
      const int cb = (sfx4(g << 2) << 4) | (((S8 >> 4) ^ PM) & 15);
      const int lb = (S8 ^ PM) & 15;
      const int qb = (cb << 4) | lb;
#pragma unroll
      for (int dd = 0; dd < 4; ++dd) {
        const float pr = fmaf(cr[dd], cr[dd], ci[dd] * ci[dd]);
        *(float*)(smb + ((qb ^ qK(dd)) << 2)) = pr;
      }
    }
  }
  __syncthreads();   // RAW: writes visible before next sweep's reads
}

__global__ __launch_bounds__(BLK) void qsim_kernel(const float* __restrict__ x,
                                                   const float* __restrict__ gt,
                                                   float* __restrict__ out) {
  __shared__ __align__(16) unsigned smu[8192];   // 32 KiB state plane
  char* smb = (char*)smu;
  const int T = threadIdx.x, b = blockIdx.x;

  // ---- init: product state (RX encoding folded), write split-bf16, P0 layout
  {
    float cs[NQ], sn[NQ];
#pragma unroll
    for (int i = 0; i < NQ; ++i) __sincosf(x[b * NQ + i] * 0.5f, &sn[i], &cs[i]);
    float hm = 1.0f;                    // wires 0..7 <-> T bits 7..0
#pragma unroll
    for (int i = 0; i < 8; ++i) hm *= ((T >> (7 - i)) & 1) ? sn[i] : cs[i];
    float mag[16];
    mag[0] = hm;                        // wires 8..11 <-> l bits 3..0
#pragma unroll
    for (int bb = 0; bb < 4; ++bb)
#pragma unroll
      for (int j = 0; j < (1 << bb); ++j) {
        mag[j | (1 << bb)] = mag[j] * sn[11 - bb];
        mag[j]             = mag[j] * cs[11 - bb];
      }
    const int pt = __popc(T);
    float re[16], im[16];
#pragma unroll
    for (int l = 0; l < 16; ++l) {      // * (-i)^popcount(q)
      const float m = mag[l];
      const int k = (pt + __popc(l)) & 3;
      re[l] = (k & 1) ? 0.f : ((k & 2) ? -m : m);
      im[l] = (k & 1) ? ((k & 2) ? m : -m) : 0.f;
    }
#pragma unroll
    for (int cc = 0; cc < 2; ++cc)
#pragma unroll
      for (int l = 0; l < 16; l += 2) {
        u32x2v wv2;
        wv2.x = packsplit(cc ? im[l]     : re[l]);
        wv2.y = packsplit(cc ? im[l + 1] : re[l + 1]);
        *(u32x2v*)(smb + pa(T, cc, l)) = wv2;
      }
  }
  __syncthreads();

#pragma unroll 1
  for (int d = 0; d < DEPTH - 1; ++d) {
    do_sweep<0, false>(d, gt, smb, T);
    do_sweep<1, false>(d, gt, smb, T);
    do_sweep<2, false>(d, gt, smb, T);
  }
  do_sweep<0, false>(DEPTH - 1, gt, smb, T);
  do_sweep<1, false>(DEPTH - 1, gt, smb, T);
  do_sweep<2, true >(DEPTH - 1, gt, smb, T);

  // ---- output: probs in smf[0..4096); q = T*16 + j ----
  const float* smf = (const float*)smu;
  float tot = 0.f, s0 = 0.f, s1 = 0.f, s2 = 0.f, s3 = 0.f;
#pragma unroll
  for (int j = 0; j < 16; ++j) {
    const float p = smf[T * 16 + j];
    tot += p;
    s0 += (j & 1) ? -p : p;
    s1 += (j & 2) ? -p : p;
    s2 += (j & 4) ? -p : p;
    s3 += (j & 8) ? -p : p;
  }
  float v[NQ];
#pragma unroll
  for (int w = 0; w < 8; ++w) v[w] = ((T >> (7 - w)) & 1) ? -tot : tot;
  v[8] = s3; v[9] = s2; v[10] = s1; v[11] = s0;
#pragma unroll
  for (int w = 0; w < NQ; ++w)
#pragma unroll
    for (int o = 32; o > 0; o >>= 1) v[w] += __shfl_xor(v[w], o);
  float* scr = (float*)(smb + 16384);   // scratch above probs region
  if ((T & 63) == 0)
#pragma unroll
    for (int w = 0; w < NQ; ++w) scr[w * 4 + (T >> 6)] = v[w];
  __syncthreads();
  if (T < NQ) out[b * NQ + T] = (scr[T * 4 + 0] + scr[T * 4 + 1]) +
                                (scr[T * 4 + 2] + scr[T * 4 + 3]);
}

extern "C" void kernel_launch(void* const* d_in, const int* in_sizes, int n_in,
                              void* d_out, int out_size, void* d_ws, size_t ws_size,
                              hipStream_t stream) {
  const float* x      = (const float*)d_in[0];
  const float* params = (const float*)d_in[1];
  float* out          = (float*)d_out;
  float* gt           = (float*)d_ws;    // 18 sweeps * 4 mats * 64 lanes * 16B = 72 KB
  const int B = in_sizes[0] / NQ;        // 4096
  prep_kernel<<<18, 64, 0, stream>>>(params, gt);
  qsim_kernel<<<B, BLK, 0, stream>>>(x, gt, out);
}